// Round 5
// baseline (115.684 us; speedup 1.0000x reference)
//
#include <hip/hip_runtime.h>
#include <hip/hip_bf16.h>

#define NN 4096
#define SJ 16
#define JCH (NN / SJ)        // 256
#define JSTEP 64
#define NSTEPS (JCH / JSTEP) // 4
#define LOG2E 1.44269504f

typedef __attribute__((ext_vector_type(4))) float f32x4;
typedef __attribute__((ext_vector_type(4))) int i32x4;
typedef __attribute__((ext_vector_type(4))) unsigned int u32x4;
typedef __attribute__((ext_vector_type(8))) short short8;

// packed bf16 conversion: 2 f32 -> 1 dword (native v_cvt_pk_bf16_f32)
__device__ __forceinline__ unsigned pk2(float a, float b) {
    float2 t; t.x = a; t.y = b;
    __hip_bfloat162 h = __float22bfloat162_rn(t);
    unsigned r;
    __builtin_memcpy(&r, &h, 4);
    return r;
}

__device__ __forceinline__ short8 load8_bf(const float* __restrict__ p) {
    f32x4 a = *(const f32x4*)p;
    f32x4 b = *(const f32x4*)(p + 4);
    u32x4 v = {pk2(a[0], a[1]), pk2(a[2], a[3]), pk2(b[0], b[1]), pk2(b[2], b[3])};
    return __builtin_bit_cast(short8, v);
}

// Kernel 1: h = x @ W^T (bf16 MFMA). Fused epilogue computes the softmax tables:
//   Rt[h][i] = exp2(-0.8*es*log2e)   (per-row ratio; A_i = exp(es) cancels in softmax)
//   Bt[h][j] = exp2(ed*log2e)        (= exp(ed))
//   Dt[h][j] = exp2(0.2*ed*log2e)    (= exp(0.2 ed))
// so that exp(leakyrelu(es_i+ed_j)) = A_i * max(Bt_j, Rt_i*Dt_j).
// Also writes transposed bf16 hT[h*32+d][j].
__global__ __launch_bounds__(256) void k1_proj(
        const float* __restrict__ x, const float* __restrict__ W,
        const float* __restrict__ asrc, const float* __restrict__ adst,
        unsigned short* __restrict__ hT, float* __restrict__ Rt,
        float* __restrict__ Bt, float* __restrict__ Dt) {
    const int ibase = blockIdx.x * 16;
    const int w = threadIdx.x >> 6;
    const int lane = threadIdx.x & 63;
    const int grp = lane >> 4, li = lane & 15;

    const float* xrow = x + (ibase + li) * 128;
    const float* w0 = W + (w * 32 + li) * 128;
    const float* w1 = W + (w * 32 + 16 + li) * 128;

    f32x4 c0 = {0.f, 0.f, 0.f, 0.f}, c1 = {0.f, 0.f, 0.f, 0.f};
#pragma unroll
    for (int ko = 0; ko < 128; ko += 32) {
        const int kk = ko + grp * 8;
        short8 a = load8_bf(xrow + kk);
        short8 b0 = load8_bf(w0 + kk);
        short8 b1 = load8_bf(w1 + kk);
        c0 = __builtin_amdgcn_mfma_f32_16x16x32_bf16(a, b0, c0, 0, 0, 0);
        c1 = __builtin_amdgcn_mfma_f32_16x16x32_bf16(a, b1, c1, 0, 0, 0);
    }
    const float as0 = asrc[w * 32 + li], as1 = asrc[w * 32 + 16 + li];
    const float ad0 = adst[w * 32 + li], ad1 = adst[w * 32 + 16 + li];
    float pes[4], ped[4];
#pragma unroll
    for (int r = 0; r < 4; ++r) {
        pes[r] = c0[r] * as0 + c1[r] * as1;
        ped[r] = c0[r] * ad0 + c1[r] * ad1;
    }
#pragma unroll
    for (int m = 1; m < 16; m <<= 1) {
#pragma unroll
        for (int r = 0; r < 4; ++r) {
            pes[r] += __shfl_xor(pes[r], m);
            ped[r] += __shfl_xor(ped[r], m);
        }
    }
    if (li == 0) {
#pragma unroll
        for (int r = 0; r < 4; ++r) {
            const int row = ibase + grp * 4 + r;
            Rt[w * NN + row] = __builtin_amdgcn_exp2f(-0.8f * LOG2E * pes[r]);
            Bt[w * NN + row] = __builtin_amdgcn_exp2f(LOG2E * ped[r]);
            Dt[w * NN + row] = __builtin_amdgcn_exp2f(0.2f * LOG2E * ped[r]);
        }
    }
#pragma unroll
    for (int r = 0; r < 4; ++r) {
        const int row = ibase + grp * 4 + r;
        hT[(w * 32 + li) * NN + row] = (unsigned short)__builtin_bit_cast(unsigned short, __float2bfloat16(c0[r]));
        hT[(w * 32 + 16 + li) * NN + row] = (unsigned short)__builtin_bit_cast(unsigned short, __float2bfloat16(c1[r]));
    }
}

// q = adj * max(B, R*D): 4 VALU per element, no transcendental.
__device__ __forceinline__ short8 buildQ(float R,
                                         const f32x4 B0, const f32x4 B1,
                                         const f32x4 D0, const f32x4 D1,
                                         const i32x4 alo, const i32x4 ahi) {
    float p[8];
#pragma unroll
    for (int e = 0; e < 4; ++e) {
        float m = fmaxf(B0[e], R * D0[e]);
        unsigned bits = __builtin_bit_cast(unsigned, m) & (0u - (unsigned)alo[e]);
        p[e] = __builtin_bit_cast(float, bits);
    }
#pragma unroll
    for (int e = 0; e < 4; ++e) {
        float m = fmaxf(B1[e], R * D1[e]);
        unsigned bits = __builtin_bit_cast(unsigned, m) & (0u - (unsigned)ahi[e]);
        p[4 + e] = __builtin_bit_cast(float, bits);
    }
    u32x4 u = {pk2(p[0], p[1]), pk2(p[2], p[3]), pk2(p[4], p[5]), pk2(p[6], p[7])};
    return __builtin_bit_cast(short8, u);
}

// Kernel 3: main. Grid (128 i-tiles, SJ j-chunks) x 256 thr. Wave = head.
// adj tile [32 rows][64 j] staged via global_load_lds, double-buffered, 1
// barrier/step. XOR chunk swizzle (c = p ^ (row&15)) on the GLOBAL source
// (LDS dest linear, rule 21), inverted on the ds_read.
__global__ __launch_bounds__(256, 6) void k3_main(
        const int* __restrict__ adj, const unsigned short* __restrict__ hT,
        const float* __restrict__ Rt, const float* __restrict__ Bt,
        const float* __restrict__ Dt,
        float* __restrict__ numer, float* __restrict__ denom) {
    __shared__ unsigned int adjbuf[2][32 * 64];   // 2 x 8 KB

    const int ibase = blockIdx.x * 32;
    const int jstart = blockIdx.y * JCH;
    const int head = threadIdx.x >> 6;
    const int lane = threadIdx.x & 63;
    const int grp = lane >> 4, li = lane & 15;
    const int sub = lane >> 4, p = lane & 15;     // staging roles

    const float R0 = Rt[head * NN + ibase + li];
    const float R1 = Rt[head * NN + ibase + 16 + li];
    const float* Bp = Bt + head * NN;
    const float* Dp = Dt + head * NN;
    const unsigned short* h0 = hT + (head * 32 + li) * NN;
    const unsigned short* h1 = hT + (head * 32 + 16 + li) * NN;
    const unsigned int* adju = (const unsigned int*)adj;

    f32x4 c00 = {0.f,0.f,0.f,0.f}, c01 = {0.f,0.f,0.f,0.f};
    f32x4 c10 = {0.f,0.f,0.f,0.f}, c11 = {0.f,0.f,0.f,0.f};
    f32x4 dn0 = {0.f,0.f,0.f,0.f}, dn1 = {0.f,0.f,0.f,0.f};
    short8 bones;
#pragma unroll
    for (int e = 0; e < 8; ++e) bones[e] = (short)0x3F80;  // bf16 1.0

    // wave `head` stages rows head*8 .. head*8+8; row R, chunk-position p holds
    // global chunk c = p ^ (R&15); LDS dest linear.
    auto stage = [&](unsigned int* dst, int jb) {
#pragma unroll
        for (int k = 0; k < 2; ++k) {
            const int R = head * 8 + k * 4 + sub;
            const int c = p ^ (R & 15);
            const unsigned int* g = adju + (size_t)(ibase + R) * NN + jb + c * 4;
            __builtin_amdgcn_global_load_lds(g, dst + (head * 8 + k * 4) * 64, 16, 0, 0);
        }
    };

    unsigned int* cur = &adjbuf[0][0];
    unsigned int* nxt = &adjbuf[1][0];

    stage(cur, jstart);
    __syncthreads();   // full vmcnt drain before first read

    for (int t = 0; t < NSTEPS; ++t) {
        const int jb = jstart + t * JSTEP;
        if (t + 1 < NSTEPS) stage(nxt, jb + JSTEP);

#pragma unroll
        for (int ks = 0; ks < 2; ++ks) {
            const int j0 = jb + ks * 32 + grp * 8;
            const f32x4 Bv0 = *(const f32x4*)(Bp + j0);
            const f32x4 Bv1 = *(const f32x4*)(Bp + j0 + 4);
            const f32x4 Dv0 = *(const f32x4*)(Dp + j0);
            const f32x4 Dv1 = *(const f32x4*)(Dp + j0 + 4);
            const short8 b0 = *(const short8*)(h0 + j0);
            const short8 b1 = *(const short8*)(h1 + j0);

            const int c0i = ks * 8 + grp * 2;
            const i32x4 q00 = *(const i32x4*)&cur[li * 64 + (c0i ^ li) * 4];
            const i32x4 q01 = *(const i32x4*)&cur[li * 64 + ((c0i + 1) ^ li) * 4];
            const i32x4 q10 = *(const i32x4*)&cur[(li + 16) * 64 + (c0i ^ li) * 4];
            const i32x4 q11 = *(const i32x4*)&cur[(li + 16) * 64 + ((c0i + 1) ^ li) * 4];

            const short8 A0 = buildQ(R0, Bv0, Bv1, Dv0, Dv1, q00, q01);
            const short8 A1 = buildQ(R1, Bv0, Bv1, Dv0, Dv1, q10, q11);

            c00 = __builtin_amdgcn_mfma_f32_16x16x32_bf16(A0, b0, c00, 0, 0, 0);
            c01 = __builtin_amdgcn_mfma_f32_16x16x32_bf16(A0, b1, c01, 0, 0, 0);
            c10 = __builtin_amdgcn_mfma_f32_16x16x32_bf16(A1, b0, c10, 0, 0, 0);
            c11 = __builtin_amdgcn_mfma_f32_16x16x32_bf16(A1, b1, c11, 0, 0, 0);
            dn0 = __builtin_amdgcn_mfma_f32_16x16x32_bf16(A0, bones, dn0, 0, 0, 0);
            dn1 = __builtin_amdgcn_mfma_f32_16x16x32_bf16(A1, bones, dn1, 0, 0, 0);
        }

        __syncthreads();   // drains stage vmcnt; nxt ready for next iteration
        unsigned int* tmp = cur; cur = nxt; nxt = tmp;
    }

    // Epilogue: C layout col=li, row = grp*4+reg.
    const int r0 = ibase + grp * 4;
    float* nb = numer + head * 32 + li;
#pragma unroll
    for (int r = 0; r < 4; ++r) {
        atomicAdd(nb + (size_t)(r0 + r) * 128, c00[r]);
        atomicAdd(nb + (size_t)(r0 + r) * 128 + 16, c01[r]);
        atomicAdd(nb + (size_t)(r0 + 16 + r) * 128, c10[r]);
        atomicAdd(nb + (size_t)(r0 + 16 + r) * 128 + 16, c11[r]);
    }
    if (li == 0) {
#pragma unroll
        for (int r = 0; r < 4; ++r) {
            atomicAdd(denom + (r0 + r) * 4 + head, dn0[r]);
            atomicAdd(denom + (r0 + 16 + r) * 4 + head, dn1[r]);
        }
    }
}

// Kernel 4: out = numer / denom
__global__ __launch_bounds__(256) void k4_fin(const float* __restrict__ numer,
                                              const float* __restrict__ denom,
                                              float* __restrict__ out) {
    const int idx = blockIdx.x * 256 + threadIdx.x;
    const int node = idx >> 7;
    const int headc = (idx & 127) >> 5;
    out[idx] = numer[idx] / denom[node * 4 + headc];
}

extern "C" void kernel_launch(void* const* d_in, const int* in_sizes, int n_in,
                              void* d_out, int out_size, void* d_ws, size_t ws_size,
                              hipStream_t stream) {
    const float* x = (const float*)d_in[0];
    const int* adj = (const int*)d_in[1];
    const float* W = (const float*)d_in[2];
    const float* asrc = (const float*)d_in[3];
    const float* adst = (const float*)d_in[4];
    float* out = (float*)d_out;

    char* ws = (char*)d_ws;
    float* numer = (float*)ws;                                   // 2 MB
    float* denom = (float*)(ws + (size_t)2097152);               // 64 KB
    float* Rt = (float*)(ws + (size_t)2097152 + 65536);          // 64 KB
    float* Bt = (float*)(ws + (size_t)2097152 + 131072);         // 64 KB
    float* Dt = (float*)(ws + (size_t)2097152 + 196608);         // 64 KB
    unsigned short* hT = (unsigned short*)(ws + (size_t)2097152 + 262144);  // 1 MB

    (void)hipMemsetAsync(numer, 0, 2097152 + 65536, stream);     // zero accumulators
    k1_proj<<<256, 256, 0, stream>>>(x, W, asrc, adst, hT, Rt, Bt, Dt);
    k3_main<<<dim3(128, SJ), 256, 0, stream>>>(adj, hT, Rt, Bt, Dt, numer, denom);
    k4_fin<<<2048, 256, 0, stream>>>(numer, denom, out);
}

// Round 6
// 68.537 us; speedup vs baseline: 1.6879x; 1.6879x over previous
//
#include <hip/hip_runtime.h>
#include <hip/hip_bf16.h>

#define NN 4096
#define SJ 8
#define JCH (NN / SJ)        // 512
#define JSTEP 128
#define NSTEPS (JCH / JSTEP) // 4
#define LOG2E 1.44269504f

typedef __attribute__((ext_vector_type(4))) float f32x4;
typedef __attribute__((ext_vector_type(4))) int i32x4;
typedef __attribute__((ext_vector_type(4))) unsigned int u32x4;
typedef __attribute__((ext_vector_type(8))) short short8;

// packed bf16 conversion: 2 f32 -> 1 dword (native v_cvt_pk_bf16_f32)
__device__ __forceinline__ unsigned pk2(float a, float b) {
    float2 t; t.x = a; t.y = b;
    __hip_bfloat162 h = __float22bfloat162_rn(t);
    unsigned r;
    __builtin_memcpy(&r, &h, 4);
    return r;
}

__device__ __forceinline__ short8 load8_bf(const float* __restrict__ p) {
    f32x4 a = *(const f32x4*)p;
    f32x4 b = *(const f32x4*)(p + 4);
    u32x4 v = {pk2(a[0], a[1]), pk2(a[2], a[3]), pk2(b[0], b[1]), pk2(b[2], b[3])};
    return __builtin_bit_cast(short8, v);
}

// Kernel 1: h = x @ W^T (bf16 MFMA). Fused epilogue computes softmax tables:
//   Rt[h][i] = exp(-0.8*es)   (A_i = exp(es) cancels in the softmax ratio)
//   Bt[h][j] = exp(ed), Dt[h][j] = exp(0.2*ed)
// so exp(leakyrelu(es_i+ed_j)) = A_i * max(Bt_j, Rt_i*Dt_j).
// Also writes transposed bf16 hT[h*32+d][j].
__global__ __launch_bounds__(256) void k1_proj(
        const float* __restrict__ x, const float* __restrict__ W,
        const float* __restrict__ asrc, const float* __restrict__ adst,
        unsigned short* __restrict__ hT, float* __restrict__ Rt,
        float* __restrict__ Bt, float* __restrict__ Dt) {
    const int ibase = blockIdx.x * 16;
    const int w = threadIdx.x >> 6;
    const int lane = threadIdx.x & 63;
    const int grp = lane >> 4, li = lane & 15;

    const float* xrow = x + (ibase + li) * 128;
    const float* w0 = W + (w * 32 + li) * 128;
    const float* w1 = W + (w * 32 + 16 + li) * 128;

    f32x4 c0 = {0.f, 0.f, 0.f, 0.f}, c1 = {0.f, 0.f, 0.f, 0.f};
#pragma unroll
    for (int ko = 0; ko < 128; ko += 32) {
        const int kk = ko + grp * 8;
        short8 a = load8_bf(xrow + kk);
        short8 b0 = load8_bf(w0 + kk);
        short8 b1 = load8_bf(w1 + kk);
        c0 = __builtin_amdgcn_mfma_f32_16x16x32_bf16(a, b0, c0, 0, 0, 0);
        c1 = __builtin_amdgcn_mfma_f32_16x16x32_bf16(a, b1, c1, 0, 0, 0);
    }
    const float as0 = asrc[w * 32 + li], as1 = asrc[w * 32 + 16 + li];
    const float ad0 = adst[w * 32 + li], ad1 = adst[w * 32 + 16 + li];
    float pes[4], ped[4];
#pragma unroll
    for (int r = 0; r < 4; ++r) {
        pes[r] = c0[r] * as0 + c1[r] * as1;
        ped[r] = c0[r] * ad0 + c1[r] * ad1;
    }
#pragma unroll
    for (int m = 1; m < 16; m <<= 1) {
#pragma unroll
        for (int r = 0; r < 4; ++r) {
            pes[r] += __shfl_xor(pes[r], m);
            ped[r] += __shfl_xor(ped[r], m);
        }
    }
    if (li == 0) {
#pragma unroll
        for (int r = 0; r < 4; ++r) {
            const int row = ibase + grp * 4 + r;
            Rt[w * NN + row] = __builtin_amdgcn_exp2f(-0.8f * LOG2E * pes[r]);
            Bt[w * NN + row] = __builtin_amdgcn_exp2f(LOG2E * ped[r]);
            Dt[w * NN + row] = __builtin_amdgcn_exp2f(0.2f * LOG2E * ped[r]);
        }
    }
#pragma unroll
    for (int r = 0; r < 4; ++r) {
        const int row = ibase + grp * 4 + r;
        hT[(w * 32 + li) * NN + row] = (unsigned short)__builtin_bit_cast(unsigned short, __float2bfloat16(c0[r]));
        hT[(w * 32 + 16 + li) * NN + row] = (unsigned short)__builtin_bit_cast(unsigned short, __float2bfloat16(c1[r]));
    }
}

// q = adj * max(B, R*D): 4 VALU per element, no transcendental.
__device__ __forceinline__ short8 buildQ(float R,
                                         const f32x4 B0, const f32x4 B1,
                                         const f32x4 D0, const f32x4 D1,
                                         const i32x4 alo, const i32x4 ahi) {
    float p[8];
#pragma unroll
    for (int e = 0; e < 4; ++e) {
        float m = fmaxf(B0[e], R * D0[e]);
        unsigned bits = __builtin_bit_cast(unsigned, m) & (0u - (unsigned)alo[e]);
        p[e] = __builtin_bit_cast(float, bits);
    }
#pragma unroll
    for (int e = 0; e < 4; ++e) {
        float m = fmaxf(B1[e], R * D1[e]);
        unsigned bits = __builtin_bit_cast(unsigned, m) & (0u - (unsigned)ahi[e]);
        p[4 + e] = __builtin_bit_cast(float, bits);
    }
    u32x4 u = {pk2(p[0], p[1]), pk2(p[2], p[3]), pk2(p[4], p[5]), pk2(p[6], p[7])};
    return __builtin_bit_cast(short8, u);
}

// Kernel 3: main. Grid (128 i-tiles, SJ j-chunks) x 256 thr. Wave = head.
// adj tile [32 rows][128 j] staged via global_load_lds, double-buffered, 1
// barrier/step. Step compute (~1000 cy) >= HBM latency so the barrier's
// vmcnt(0) drain costs ~nothing. XOR chunk swizzle (c = p ^ (row&31)) on the
// GLOBAL source (LDS dest linear, rule 21), inverted on the ds_read.
__global__ __launch_bounds__(256) void k3_main(
        const int* __restrict__ adj, const unsigned short* __restrict__ hT,
        const float* __restrict__ Rt, const float* __restrict__ Bt,
        const float* __restrict__ Dt,
        float* __restrict__ numer, float* __restrict__ denom) {
    __shared__ unsigned int adjbuf[2][32 * 128];   // 2 x 16 KB

    const int ibase = blockIdx.x * 32;
    const int jstart = blockIdx.y * JCH;
    const int head = threadIdx.x >> 6;
    const int lane = threadIdx.x & 63;
    const int grp = lane >> 4, li = lane & 15;
    const int sub = lane >> 5, p = lane & 31;     // staging roles: 32 chunks/row

    const float R0 = Rt[head * NN + ibase + li];
    const float R1 = Rt[head * NN + ibase + 16 + li];
    const float* Bp = Bt + head * NN;
    const float* Dp = Dt + head * NN;
    const unsigned short* h0 = hT + (head * 32 + li) * NN;
    const unsigned short* h1 = hT + (head * 32 + 16 + li) * NN;
    const unsigned int* adju = (const unsigned int*)adj;

    f32x4 c00 = {0.f,0.f,0.f,0.f}, c01 = {0.f,0.f,0.f,0.f};
    f32x4 c10 = {0.f,0.f,0.f,0.f}, c11 = {0.f,0.f,0.f,0.f};
    f32x4 dn0 = {0.f,0.f,0.f,0.f}, dn1 = {0.f,0.f,0.f,0.f};
    short8 bones;
#pragma unroll
    for (int e = 0; e < 8; ++e) bones[e] = (short)0x3F80;  // bf16 1.0

    // wave `head` stages rows head*8 .. head*8+8 (2 rows per issue, 4 issues).
    // Row R's chunk-position p holds global chunk c = p ^ (R&31); LDS linear.
    auto stage = [&](unsigned int* dst, int jb) {
#pragma unroll
        for (int k = 0; k < 4; ++k) {
            const int R = head * 8 + k * 2 + sub;
            const int c = p ^ (R & 31);
            const unsigned int* g = adju + (size_t)(ibase + R) * NN + jb + c * 4;
            __builtin_amdgcn_global_load_lds(g, dst + (head * 8 + k * 2) * 128, 16, 0, 0);
        }
    };

    unsigned int* cur = &adjbuf[0][0];
    unsigned int* nxt = &adjbuf[1][0];

    stage(cur, jstart);
    __syncthreads();   // full vmcnt drain before first read

    for (int t = 0; t < NSTEPS; ++t) {
        const int jb = jstart + t * JSTEP;
        if (t + 1 < NSTEPS) stage(nxt, jb + JSTEP);

#pragma unroll
        for (int ks = 0; ks < 4; ++ks) {
            const int j0 = jb + ks * 32 + grp * 8;
            const f32x4 Bv0 = *(const f32x4*)(Bp + j0);
            const f32x4 Bv1 = *(const f32x4*)(Bp + j0 + 4);
            const f32x4 Dv0 = *(const f32x4*)(Dp + j0);
            const f32x4 Dv1 = *(const f32x4*)(Dp + j0 + 4);
            const short8 b0 = *(const short8*)(h0 + j0);
            const short8 b1 = *(const short8*)(h1 + j0);

            const int cb = ks * 8 + grp * 2;
            const i32x4 q00 = *(const i32x4*)&cur[li * 128 + (cb ^ li) * 4];
            const i32x4 q01 = *(const i32x4*)&cur[li * 128 + ((cb + 1) ^ li) * 4];
            const i32x4 q10 = *(const i32x4*)&cur[(li + 16) * 128 + (cb ^ (li + 16)) * 4];
            const i32x4 q11 = *(const i32x4*)&cur[(li + 16) * 128 + ((cb + 1) ^ (li + 16)) * 4];

            const short8 A0 = buildQ(R0, Bv0, Bv1, Dv0, Dv1, q00, q01);
            const short8 A1 = buildQ(R1, Bv0, Bv1, Dv0, Dv1, q10, q11);

            c00 = __builtin_amdgcn_mfma_f32_16x16x32_bf16(A0, b0, c00, 0, 0, 0);
            c01 = __builtin_amdgcn_mfma_f32_16x16x32_bf16(A0, b1, c01, 0, 0, 0);
            c10 = __builtin_amdgcn_mfma_f32_16x16x32_bf16(A1, b0, c10, 0, 0, 0);
            c11 = __builtin_amdgcn_mfma_f32_16x16x32_bf16(A1, b1, c11, 0, 0, 0);
            dn0 = __builtin_amdgcn_mfma_f32_16x16x32_bf16(A0, bones, dn0, 0, 0, 0);
            dn1 = __builtin_amdgcn_mfma_f32_16x16x32_bf16(A1, bones, dn1, 0, 0, 0);
        }

        __syncthreads();   // drains stage vmcnt; nxt ready for next iteration
        unsigned int* tmp = cur; cur = nxt; nxt = tmp;
    }

    // Epilogue: C layout col=li, row = grp*4+reg.
    const int r0 = ibase + grp * 4;
    float* nb = numer + head * 32 + li;
#pragma unroll
    for (int r = 0; r < 4; ++r) {
        atomicAdd(nb + (size_t)(r0 + r) * 128, c00[r]);
        atomicAdd(nb + (size_t)(r0 + r) * 128 + 16, c01[r]);
        atomicAdd(nb + (size_t)(r0 + 16 + r) * 128, c10[r]);
        atomicAdd(nb + (size_t)(r0 + 16 + r) * 128 + 16, c11[r]);
    }
    if (li == 0) {
#pragma unroll
        for (int r = 0; r < 4; ++r) {
            atomicAdd(denom + (r0 + r) * 4 + head, dn0[r]);
            atomicAdd(denom + (r0 + 16 + r) * 4 + head, dn1[r]);
        }
    }
}

// Kernel 4: out = numer / denom
__global__ __launch_bounds__(256) void k4_fin(const float* __restrict__ numer,
                                              const float* __restrict__ denom,
                                              float* __restrict__ out) {
    const int idx = blockIdx.x * 256 + threadIdx.x;
    const int node = idx >> 7;
    const int headc = (idx & 127) >> 5;
    out[idx] = numer[idx] / denom[node * 4 + headc];
}

extern "C" void kernel_launch(void* const* d_in, const int* in_sizes, int n_in,
                              void* d_out, int out_size, void* d_ws, size_t ws_size,
                              hipStream_t stream) {
    const float* x = (const float*)d_in[0];
    const int* adj = (const int*)d_in[1];
    const float* W = (const float*)d_in[2];
    const float* asrc = (const float*)d_in[3];
    const float* adst = (const float*)d_in[4];
    float* out = (float*)d_out;

    char* ws = (char*)d_ws;
    float* numer = (float*)ws;                                   // 2 MB
    float* denom = (float*)(ws + (size_t)2097152);               // 64 KB
    float* Rt = (float*)(ws + (size_t)2097152 + 65536);          // 64 KB
    float* Bt = (float*)(ws + (size_t)2097152 + 131072);         // 64 KB
    float* Dt = (float*)(ws + (size_t)2097152 + 196608);         // 64 KB
    unsigned short* hT = (unsigned short*)(ws + (size_t)2097152 + 262144);  // 1 MB

    (void)hipMemsetAsync(numer, 0, 2097152 + 65536, stream);     // zero accumulators
    k1_proj<<<256, 256, 0, stream>>>(x, W, asrc, adst, hT, Rt, Bt, Dt);
    k3_main<<<dim3(128, SJ), 256, 0, stream>>>(adj, hT, Rt, Bt, Dt, numer, denom);
    k4_fin<<<2048, 256, 0, stream>>>(numer, denom, out);
}

// Round 7
// 57.934 us; speedup vs baseline: 1.9968x; 1.1830x over previous
//
#include <hip/hip_runtime.h>
#include <hip/hip_bf16.h>

#define NN 4096
#define SJ 8
#define JCH (NN / SJ)        // 512
#define JSTEP 64
#define NSTEPS (JCH / JSTEP) // 8
#define LOG2E 1.44269504f

typedef __attribute__((ext_vector_type(4))) float f32x4;
typedef __attribute__((ext_vector_type(4))) int i32x4;
typedef __attribute__((ext_vector_type(4))) unsigned int u32x4;
typedef __attribute__((ext_vector_type(8))) short short8;

// packed bf16 pair: (lo=bf16(a), hi=bf16(b)) in one dword (v_cvt_pk_bf16_f32)
__device__ __forceinline__ unsigned pk2(float a, float b) {
    float2 t; t.x = a; t.y = b;
    __hip_bfloat162 h = __float22bfloat162_rn(t);
    unsigned r;
    __builtin_memcpy(&r, &h, 4);
    return r;
}

__device__ __forceinline__ short8 load8_bf(const float* __restrict__ p) {
    f32x4 a = *(const f32x4*)p;
    f32x4 b = *(const f32x4*)(p + 4);
    u32x4 v = {pk2(a[0], a[1]), pk2(a[2], a[3]), pk2(b[0], b[1]), pk2(b[2], b[3])};
    return __builtin_bit_cast(short8, v);
}

// Kernel 1: h = x @ W^T (bf16 MFMA). Epilogue:
//   Rt[h][i]  = exp(-0.8*es_i)                  (f32; exp(es) factor cancels in softmax)
//   BDt[h][j] = pack_bf16(exp(ed_j), exp(0.2*ed_j))
//   hT[h*32+d][j] = bf16 h — transposed via per-wave LDS tile, coalesced 16B stores.
__global__ __launch_bounds__(256) void k1_proj(
        const float* __restrict__ x, const float* __restrict__ W,
        const float* __restrict__ asrc, const float* __restrict__ adst,
        unsigned short* __restrict__ hT, float* __restrict__ Rt,
        unsigned* __restrict__ BDt) {
    __shared__ unsigned short ttile[4][32][16];   // 4 KB: per-wave transpose tile
    const int ibase = blockIdx.x * 16;
    const int w = threadIdx.x >> 6;
    const int lane = threadIdx.x & 63;
    const int grp = lane >> 4, li = lane & 15;

    const float* xrow = x + (ibase + li) * 128;
    const float* w0 = W + (w * 32 + li) * 128;
    const float* w1 = W + (w * 32 + 16 + li) * 128;

    f32x4 c0 = {0.f, 0.f, 0.f, 0.f}, c1 = {0.f, 0.f, 0.f, 0.f};
#pragma unroll
    for (int ko = 0; ko < 128; ko += 32) {
        const int kk = ko + grp * 8;
        short8 a = load8_bf(xrow + kk);
        short8 b0 = load8_bf(w0 + kk);
        short8 b1 = load8_bf(w1 + kk);
        c0 = __builtin_amdgcn_mfma_f32_16x16x32_bf16(a, b0, c0, 0, 0, 0);
        c1 = __builtin_amdgcn_mfma_f32_16x16x32_bf16(a, b1, c1, 0, 0, 0);
    }
    const float as0 = asrc[w * 32 + li], as1 = asrc[w * 32 + 16 + li];
    const float ad0 = adst[w * 32 + li], ad1 = adst[w * 32 + 16 + li];
    float pes[4], ped[4];
#pragma unroll
    for (int r = 0; r < 4; ++r) {
        pes[r] = c0[r] * as0 + c1[r] * as1;
        ped[r] = c0[r] * ad0 + c1[r] * ad1;
    }
#pragma unroll
    for (int m = 1; m < 16; m <<= 1) {
#pragma unroll
        for (int r = 0; r < 4; ++r) {
            pes[r] += __shfl_xor(pes[r], m);
            ped[r] += __shfl_xor(ped[r], m);
        }
    }
    if (li == 0) {
#pragma unroll
        for (int r = 0; r < 4; ++r) {
            const int row = ibase + grp * 4 + r;
            Rt[w * NN + row] = __builtin_amdgcn_exp2f(-0.8f * LOG2E * pes[r]);
            const float Bv = __builtin_amdgcn_exp2f(LOG2E * ped[r]);
            const float Dv = __builtin_amdgcn_exp2f(0.2f * LOG2E * ped[r]);
            BDt[w * NN + row] = pk2(Bv, Dv);
        }
    }
    // transpose h into [d][row16] via LDS, then coalesced 16B global stores
    unsigned short* tw = &ttile[w][0][0];
    {
        uint2 v0; v0.x = pk2(c0[0], c0[1]); v0.y = pk2(c0[2], c0[3]);
        uint2 v1; v1.x = pk2(c1[0], c1[1]); v1.y = pk2(c1[2], c1[3]);
        *(uint2*)&tw[li * 16 + grp * 4] = v0;
        *(uint2*)&tw[(li + 16) * 16 + grp * 4] = v1;
    }
    __syncthreads();
    const int d = lane >> 1, half = lane & 1;
    u32x4 v = *(const u32x4*)&ttile[w][d][half * 8];
    *(u32x4*)(hT + (size_t)(w * 32 + d) * NN + ibase + half * 8) = v;
}

// per-step register payload: hT fragments + packed B/D slices (zero in-loop vmem)
struct SR {
    short8 t00, t01, t10, t11;   // hT rows d=li (ks=0,1), d=li+16 (ks=0,1)
    u32x4 b0a, b0b, b1a, b1b;    // BDt slices: ks=0 (j0..j0+8), ks=1
};

// q = adj * max(B, R*D) from packed bf16 {B,D}: shl/and unpack + mul/max/mask.
__device__ __forceinline__ short8 buildQ(float R, const u32x4 ba, const u32x4 bb,
                                         const i32x4 alo, const i32x4 ahi) {
    float p[8];
#pragma unroll
    for (int e = 0; e < 4; ++e) {
        const unsigned v = ba[e];
        const float B = __builtin_bit_cast(float, v << 16);
        const float D = __builtin_bit_cast(float, v & 0xFFFF0000u);
        const float m = fmaxf(B, R * D);
        p[e] = __builtin_bit_cast(float, __builtin_bit_cast(unsigned, m) & (0u - (unsigned)alo[e]));
    }
#pragma unroll
    for (int e = 0; e < 4; ++e) {
        const unsigned v = bb[e];
        const float B = __builtin_bit_cast(float, v << 16);
        const float D = __builtin_bit_cast(float, v & 0xFFFF0000u);
        const float m = fmaxf(B, R * D);
        p[4 + e] = __builtin_bit_cast(float, __builtin_bit_cast(unsigned, m) & (0u - (unsigned)ahi[e]));
    }
    u32x4 u = {pk2(p[0], p[1]), pk2(p[2], p[3]), pk2(p[4], p[5]), pk2(p[6], p[7])};
    return __builtin_bit_cast(short8, u);
}

// Kernel 3: grid (128 i-tiles, SJ) x 256 thr, wave = head, 32 rows/block.
// Depth-2 counted-vmcnt pipeline: adj triple-buffered via global_load_lds;
// per iter: [reg-load tables t+1] [stage adj t+2] [compute t: NO vmem]
// [s_waitcnt vmcnt(2)] [raw s_barrier]. stage(t+1) is oldest outstanding ->
// guaranteed drained by vmcnt(2); stage(t+2) stays in flight across barrier.
__global__ __launch_bounds__(256) void k3_main(
        const int* __restrict__ adj, const unsigned short* __restrict__ hT,
        const float* __restrict__ Rt, const unsigned* __restrict__ BDt,
        float* __restrict__ numer, float* __restrict__ denom) {
    __shared__ unsigned int adjbuf[3][32 * 64];   // 3 x 8 KB

    const int ibase = blockIdx.x * 32;
    const int jstart = blockIdx.y * JCH;
    const int head = threadIdx.x >> 6;
    const int lane = threadIdx.x & 63;
    const int grp = lane >> 4, li = lane & 15;
    const int sub = lane >> 4, p = lane & 15;     // staging roles (16 chunks/row)

    const float R0 = Rt[head * NN + ibase + li];
    const float R1 = Rt[head * NN + ibase + 16 + li];
    const unsigned short* h0 = hT + (size_t)(head * 32 + li) * NN;
    const unsigned short* h1 = hT + (size_t)(head * 32 + 16 + li) * NN;
    const unsigned* bd = BDt + head * NN;
    const unsigned int* adju = (const unsigned int*)adj;

    f32x4 c00 = {0.f,0.f,0.f,0.f}, c01 = {0.f,0.f,0.f,0.f};
    f32x4 c10 = {0.f,0.f,0.f,0.f}, c11 = {0.f,0.f,0.f,0.f};
    f32x4 dn0 = {0.f,0.f,0.f,0.f}, dn1 = {0.f,0.f,0.f,0.f};
    short8 bones;
#pragma unroll
    for (int e = 0; e < 8; ++e) bones[e] = (short)0x3F80;  // bf16 1.0

    // wave `head` stages rows head*8..+8; chunk-position p holds global chunk
    // c = p ^ (row&15) (LDS dest linear per rule 21); inverted on ds_read.
    auto stage = [&](unsigned int* dst, int jb) {
#pragma unroll
        for (int k = 0; k < 2; ++k) {
            const int Rw = head * 8 + k * 4 + sub;
            const int c = p ^ (Rw & 15);
            const unsigned int* g = adju + (size_t)(ibase + Rw) * NN + jb + c * 4;
            __builtin_amdgcn_global_load_lds(g, dst + (head * 8 + k * 4) * 64, 16, 0, 0);
        }
    };
    auto loadR = [&](int jb) {
        SR r;
        r.t00 = *(const short8*)(h0 + jb + grp * 8);
        r.t01 = *(const short8*)(h0 + jb + 32 + grp * 8);
        r.t10 = *(const short8*)(h1 + jb + grp * 8);
        r.t11 = *(const short8*)(h1 + jb + 32 + grp * 8);
        r.b0a = *(const u32x4*)(bd + jb + grp * 8);
        r.b0b = *(const u32x4*)(bd + jb + grp * 8 + 4);
        r.b1a = *(const u32x4*)(bd + jb + 32 + grp * 8);
        r.b1b = *(const u32x4*)(bd + jb + 32 + grp * 8 + 4);
        return r;
    };

    unsigned int* bA = &adjbuf[0][0];
    unsigned int* bB = &adjbuf[1][0];
    unsigned int* bC = &adjbuf[2][0];

    stage(bA, jstart);                 // 2 issues (oldest)
    SR Rg = loadR(jstart);             // 8 issues
    stage(bB, jstart + JSTEP);         // 2 issues (newest)
    asm volatile("s_waitcnt vmcnt(2)" ::: "memory");   // bA + Rg ready; bB in flight
    __builtin_amdgcn_s_barrier();

    for (int t = 0; t < NSTEPS; ++t) {
        const int jb = jstart + t * JSTEP;
        SR Rn = Rg;
        if (t + 1 < NSTEPS) Rn = loadR(jb + JSTEP);
        if (t + 2 < NSTEPS) stage(bC, jb + 2 * JSTEP);

#pragma unroll
        for (int ks = 0; ks < 2; ++ks) {
            const short8 tA = ks ? Rg.t01 : Rg.t00;
            const short8 tB = ks ? Rg.t11 : Rg.t10;
            const u32x4 ba = ks ? Rg.b1a : Rg.b0a;
            const u32x4 bb = ks ? Rg.b1b : Rg.b0b;
            const int cb = ks * 8 + grp * 2;
            const i32x4 q00 = *(const i32x4*)&bA[li * 64 + (cb ^ li) * 4];
            const i32x4 q01 = *(const i32x4*)&bA[li * 64 + ((cb + 1) ^ li) * 4];
            const i32x4 q10 = *(const i32x4*)&bA[(li + 16) * 64 + (cb ^ li) * 4];
            const i32x4 q11 = *(const i32x4*)&bA[(li + 16) * 64 + ((cb + 1) ^ li) * 4];

            const short8 A0 = buildQ(R0, ba, bb, q00, q01);
            const short8 A1 = buildQ(R1, ba, bb, q10, q11);

            c00 = __builtin_amdgcn_mfma_f32_16x16x32_bf16(A0, tA, c00, 0, 0, 0);
            c01 = __builtin_amdgcn_mfma_f32_16x16x32_bf16(A0, tB, c01, 0, 0, 0);
            c10 = __builtin_amdgcn_mfma_f32_16x16x32_bf16(A1, tA, c10, 0, 0, 0);
            c11 = __builtin_amdgcn_mfma_f32_16x16x32_bf16(A1, tB, c11, 0, 0, 0);
            dn0 = __builtin_amdgcn_mfma_f32_16x16x32_bf16(A0, bones, dn0, 0, 0, 0);
            dn1 = __builtin_amdgcn_mfma_f32_16x16x32_bf16(A1, bones, dn1, 0, 0, 0);
        }

        asm volatile("s_waitcnt vmcnt(2)" ::: "memory");  // stage(t+1) drained (oldest)
        __builtin_amdgcn_s_barrier();
        unsigned int* tmp = bA; bA = bB; bB = bC; bC = tmp;
        Rg = Rn;
    }

    // Epilogue: C layout col=li, row=grp*4+reg.
    const int r0 = ibase + grp * 4;
    float* nb = numer + head * 32 + li;
#pragma unroll
    for (int r = 0; r < 4; ++r) {
        atomicAdd(nb + (size_t)(r0 + r) * 128, c00[r]);
        atomicAdd(nb + (size_t)(r0 + r) * 128 + 16, c01[r]);
        atomicAdd(nb + (size_t)(r0 + 16 + r) * 128, c10[r]);
        atomicAdd(nb + (size_t)(r0 + 16 + r) * 128 + 16, c11[r]);
    }
    if (li == 0) {
#pragma unroll
        for (int r = 0; r < 4; ++r) {
            atomicAdd(denom + (r0 + r) * 4 + head, dn0[r]);
            atomicAdd(denom + (r0 + 16 + r) * 4 + head, dn1[r]);
        }
    }
}

// Kernel 4: out = numer / denom
__global__ __launch_bounds__(256) void k4_fin(const float* __restrict__ numer,
                                              const float* __restrict__ denom,
                                              float* __restrict__ out) {
    const int idx = blockIdx.x * 256 + threadIdx.x;
    const int node = idx >> 7;
    const int headc = (idx & 127) >> 5;
    out[idx] = numer[idx] / denom[node * 4 + headc];
}

extern "C" void kernel_launch(void* const* d_in, const int* in_sizes, int n_in,
                              void* d_out, int out_size, void* d_ws, size_t ws_size,
                              hipStream_t stream) {
    const float* x = (const float*)d_in[0];
    const int* adj = (const int*)d_in[1];
    const float* W = (const float*)d_in[2];
    const float* asrc = (const float*)d_in[3];
    const float* adst = (const float*)d_in[4];
    float* out = (float*)d_out;

    char* ws = (char*)d_ws;
    float* numer = (float*)ws;                                     // 2 MB
    float* denom = (float*)(ws + (size_t)2097152);                 // 64 KB
    float* Rt = (float*)(ws + (size_t)2097152 + 65536);            // 64 KB
    unsigned* BDt = (unsigned*)(ws + (size_t)2097152 + 131072);    // 64 KB
    unsigned short* hT = (unsigned short*)(ws + (size_t)2097152 + 196608);  // 1 MB

    (void)hipMemsetAsync(numer, 0, 2097152 + 65536, stream);       // zero accumulators
    k1_proj<<<256, 256, 0, stream>>>(x, W, asrc, adst, hT, Rt, BDt);
    k3_main<<<dim3(128, SJ), 256, 0, stream>>>(adj, hT, Rt, BDt, numer, denom);
    k4_fin<<<2048, 256, 0, stream>>>(numer, denom, out);
}